// Round 15
// baseline (204.466 us; speedup 1.0000x reference)
//
#include <hip/hip_runtime.h>

typedef __attribute__((ext_vector_type(8))) __bf16 bf16x8;
typedef __attribute__((ext_vector_type(8))) unsigned short ushort8;
typedef __attribute__((ext_vector_type(4))) float f32x4;
typedef __attribute__((ext_vector_type(2))) unsigned int uint2v;

constexpr int C_ = 32, NN = 64;
constexpr int PK = 3375;              // 15^3
constexpr int K_TOT = 108000;         // C*PK
constexpr int F_TOT = 1024;
constexpr int M_TOT = 128;            // B*N
constexpr int KSTEPS = 3375;          // K_TOT/32
constexpr int CS   = 27;              // steps per chunk (125*27 = 3375 exact)
constexpr int SCH  = 125;             // real chunks
constexpr int SPAD = 128;             // padded chunks (grid 256, 3 zero-chunks)

// GEMM LDS: W [2][32][1024] bf16 (2x64KB) + A frag-order [2][4][64][16B] (2x4KB)
constexpr int WB = 65536;
constexpr int AB = 4096;

__device__ __forceinline__ unsigned short f2bf(float f) {
    unsigned int b = __builtin_bit_cast(unsigned int, f);
    b += 0x7FFFu + ((b >> 16) & 1u);      // round-to-nearest-even
    return (unsigned short)(b >> 16);
}

// ---------------- kernel 1: patch gather -> bf16 A natural [m][K] layout ---------
__global__ void extract_kernel(const float* __restrict__ x,
                               const int* __restrict__ cent,
                               unsigned short* __restrict__ Af) {
    int m = blockIdx.x;            // 0..127  (b*64+n)
    int c = blockIdx.y;            // 0..31
    int b = m >> 6, n = m & 63;
    int cx = cent[(b * NN + n) * 3 + 0];
    int cy = cent[(b * NN + n) * 3 + 1];
    int cz = cent[(b * NN + n) * 3 + 2];
    int sx = max(cx - 7, 0), ex = min(cx + 8, 96);
    int sy = max(cy - 7, 0), ey = min(cy + 8, 96);
    int sz = max(cz - 7, 0), ez = min(cz + 8, 96);
    const float* xb = x + (size_t)(b * C_ + c) * (96 * 96 * 96);
    unsigned short* Arow = Af + (size_t)m * K_TOT + (size_t)c * PK;
    for (int k = threadIdx.x; k < PK; k += blockDim.x) {
        int iz = k % 15;
        int t  = k / 15;
        int iy = t % 15;
        int ix = t / 15;
        int hx = sx + ix, wy = sy + iy, dz = sz + iz;
        float v = 0.0f;
        if (hx < ex && wy < ey && dz < ez)
            v = xb[(hx * 96 + wy) * 96 + dz];
        Arow[k] = f2bf(v);
    }
}

// ---------------- kernel 2: split-K GEMM, PURE-LINEAR W streams -------------------
// Tile M=64 x F=1024, 1024 threads (16 waves, 4/SIMD), acc 64 f32/thread.
// Block (s,mh) reads its chunk's ENTIRE W slice as one contiguous linear stream
// (128KB/step: 32 threads/row x 32 floats/thread = full 4KB rows). mh-mate
// (id differs by 8 -> same XCD) re-reads the slice from L2 (3.46MB < 4MB L2).
// W reg-staged fp32->bf16->LDS (issue-early/write-late, 1 barrier/step).
__global__ __launch_bounds__(1024, 1) void gemm_kernel(const unsigned short* __restrict__ Af,
                                                       const float* __restrict__ W,
                                                       unsigned short* __restrict__ partial) {
    __shared__ __align__(16) unsigned char smem[2 * WB + 2 * AB];   // 139,264 B
    int id = blockIdx.x;
    int mh = (id >> 3) & 1;
    int s  = (id >> 4) * 8 + (id & 7);         // 0..127; id%8 = s%8 (XCD pin)
    int tid = (int)threadIdx.x;
    unsigned short* pout = partial + (size_t)s * (M_TOT * F_TOT) + (size_t)mh * 64 * F_TOT;

    if (s >= SCH) {                             // pad chunk: zero its partial half
        for (int i = tid * 8; i < 64 * F_TOT; i += 1024 * 8)
            *reinterpret_cast<ushort8*>(pout + i) = (ushort8)(unsigned short)0;
        return;
    }
    int st0 = s * CS, st1 = st0 + CS;

    int wave = tid >> 6, lane = tid & 63;
    int fr = lane & 15, lgrp = lane >> 4;
    int r  = tid >> 5, fs = tid & 31;          // staging: W row, 16B f-group
    int f0w = wave * 64;

    f32x4 acc[4][4];                           // [mt][ft]
#pragma unroll
    for (int i = 0; i < 4; ++i)
#pragma unroll
        for (int j = 0; j < 4; ++j) acc[i][j] = (f32x4)(0.0f);

    // A-stage source for tid<256: per-lane fragment gather (R13-proven)
    const unsigned short* agbase =
        Af + (size_t)(mh * 64 + (tid >> 6) * 16 + fr) * K_TOT + lgrp * 8;

    auto LOADS = [&](int st, f32x4* v, bf16x8& av) {
        const float* p = W + ((size_t)st * 32 + r) * F_TOT + fs * 4;
#pragma unroll
        for (int j = 0; j < 8; ++j)            // 8 x 16B: thread covers its 1/32 of 4KB row
            v[j] = *reinterpret_cast<const f32x4*>(p + j * 128);
        if (tid < 256)
            av = *reinterpret_cast<const bf16x8*>(agbase + (st << 5));
    };
    auto WRITES = [&](int buf, const f32x4* v, const bf16x8& av) {
        unsigned char* wb = smem + buf * WB;
#pragma unroll
        for (int j = 0; j < 8; ++j) {
            unsigned lo = (unsigned)f2bf(v[j].x) | ((unsigned)f2bf(v[j].y) << 16);
            unsigned hi = (unsigned)f2bf(v[j].z) | ((unsigned)f2bf(v[j].w) << 16);
            uint2v w; w.x = lo; w.y = hi;      // ds_write_b64, 2-way banks (free)
            *reinterpret_cast<uint2v*>(wb + r * 2048 + (fs + j * 32) * 8) = w;
        }
        if (tid < 256)
            *reinterpret_cast<bf16x8*>(smem + 2 * WB + buf * AB
                                       + (tid >> 6) * 1024 + lane * 16) = av;
    };
    auto COMPUTE = [&](int buf) {
        const unsigned char* wb = smem + buf * WB;
        const unsigned char* ab = smem + 2 * WB + buf * AB;
        bf16x8 afrag[4];
#pragma unroll
        for (int mt = 0; mt < 4; ++mt)         // ds_read_b128, conflict-free
            afrag[mt] = *reinterpret_cast<const bf16x8*>(ab + mt * 1024 + lane * 16);
#pragma unroll
        for (int ft = 0; ft < 4; ++ft) {
            int f = f0w + ft * 16 + fr;
            ushort8 bt;
#pragma unroll
            for (int j = 0; j < 8; ++j)
                bt[j] = *reinterpret_cast<const unsigned short*>(
                            wb + (lgrp * 8 + j) * 2048 + f * 2);
            bf16x8 bfrag = __builtin_bit_cast(bf16x8, bt);
#pragma unroll
            for (int mt = 0; mt < 4; ++mt)
                acc[mt][ft] = __builtin_amdgcn_mfma_f32_16x16x32_bf16(afrag[mt], bfrag, acc[mt][ft], 0, 0, 0);
        }
    };

    {   // prologue
        f32x4 v[8]; bf16x8 av;
        LOADS(st0, v, av);
        WRITES(0, v, av);                       // compiler inserts vmcnt before use
    }
    __syncthreads();
    int cur = 0;
    for (int t = st0; t < st1; ++t) {
        f32x4 nv[8]; bf16x8 nav;
        if (t + 1 < st1) LOADS(t + 1, nv, nav); // issue early: streams during compute
        COMPUTE(cur);
        if (t + 1 < st1) WRITES(cur ^ 1, nv, nav);
        __syncthreads();
        cur ^= 1;
    }

    // --- write bf16 partials: D row = lgrp*4 + rr, col = fr (m89 mapping) ---
#pragma unroll
    for (int mt = 0; mt < 4; ++mt) {
        int mbase = mt * 16 + lgrp * 4;
#pragma unroll
        for (int ft = 0; ft < 4; ++ft) {
            int f = f0w + ft * 16 + fr;
#pragma unroll
            for (int rr = 0; rr < 4; ++rr)
                pout[(size_t)(mbase + rr) * F_TOT + f] = f2bf(acc[mt][ft][rr]);
        }
    }
}

// ---------------- kernel 3: split-K reduce (bf16 partials) + bias ----------------
__global__ void reduce_kernel(const unsigned short* __restrict__ partial,
                              const float* __restrict__ bias,
                              float* __restrict__ out, int S) {
    int i8 = (blockIdx.x * blockDim.x + threadIdx.x) * 8;
    if (i8 >= M_TOT * F_TOT) return;
    f32x4 b0 = *reinterpret_cast<const f32x4*>(bias + (i8 & (F_TOT - 1)));
    f32x4 b1 = *reinterpret_cast<const f32x4*>(bias + (i8 & (F_TOT - 1)) + 4);
    float a[8] = {b0.x, b0.y, b0.z, b0.w, b1.x, b1.y, b1.z, b1.w};
    for (int s = 0; s < S; ++s) {
        ushort8 p = *reinterpret_cast<const ushort8*>(partial + (size_t)s * (M_TOT * F_TOT) + i8);
#pragma unroll
        for (int j = 0; j < 8; ++j)
            a[j] += __builtin_bit_cast(float, (unsigned int)p[j] << 16);
    }
#pragma unroll
    for (int j = 0; j < 8; ++j) out[i8 + j] = a[j];
}

extern "C" void kernel_launch(void* const* d_in, const int* in_sizes, int n_in,
                              void* d_out, int out_size, void* d_ws, size_t ws_size,
                              hipStream_t stream) {
    const float* x    = (const float*)d_in[0];
    const int*   cent = (const int*)d_in[1];
    const float* W    = (const float*)d_in[2];
    const float* bias = (const float*)d_in[3];
    float* out = (float*)d_out;

    unsigned short* Af = (unsigned short*)d_ws;
    size_t Af_bytes = (size_t)M_TOT * K_TOT * 2;                 // 27,648,000
    unsigned short* partial = (unsigned short*)((char*)d_ws + Af_bytes);
    // partial: SPAD * 128 * 1024 * 2B = 33.6 MB (ws is ~1.77 GB)

    extract_kernel<<<dim3(M_TOT, C_), 256, 0, stream>>>(x, cent, Af);
    gemm_kernel<<<dim3(2 * SPAD), 1024, 0, stream>>>(Af, W, partial);
    reduce_kernel<<<dim3((M_TOT * F_TOT) / (256 * 8)), 256, 0, stream>>>(partial, bias, out, SPAD);
}

// Round 16
// 126.419 us; speedup vs baseline: 1.6174x; 1.6174x over previous
//
#include <hip/hip_runtime.h>

typedef __attribute__((ext_vector_type(8))) __bf16 bf16x8;
typedef __attribute__((ext_vector_type(8))) unsigned short ushort8;
typedef __attribute__((ext_vector_type(4))) float f32x4;

constexpr int C_ = 32, NN = 64;
constexpr int PK = 3375;              // 15^3
constexpr int K_TOT = 108000;         // C*PK
constexpr int F_TOT = 1024;
constexpr int M_TOT = 128;            // B*N
constexpr int KSTEPS = 3375;          // K_TOT/32

// GEMM LDS geometry (F-tile 256): W tile 32k x 256f fp32 stored as 16 row-PAIRS
// of (2048 data + 16 pad) bytes -> B-column reads 2-way aliased (free, m136).
constexpr int WPAIR  = 2064;
constexpr int WBUF   = 16 * WPAIR;    // 33,024
constexpr int ABUF   = 8192;          // 32k x 128m bf16, fragment-ordered in LDS
constexpr int RBUF   = WBUF + ABUF;   // 41,216

__device__ __forceinline__ unsigned short f2bf(float f) {
    unsigned int b = __builtin_bit_cast(unsigned int, f);
    b += 0x7FFFu + ((b >> 16) & 1u);      // round-to-nearest-even
    return (unsigned short)(b >> 16);
}

// async 16B global -> LDS (lane i lands at base + i*16; per-lane global src, m173)
__device__ __forceinline__ void async_copy16(void* lds, const void* g) {
    __builtin_amdgcn_global_load_lds(
        (const __attribute__((address_space(1))) unsigned int*)g,
        (__attribute__((address_space(3))) unsigned int*)lds, 16, 0, 0);
}
// NT variant for the dead-after-use W stream: aux=2 (CPol::NT on gfx94x+)
// -> bypass/low-priority L2+L3 fill, stop churning caches with 442MB of
// single-use data so Af/partials stay resident.
__device__ __forceinline__ void async_copy16_nt(void* lds, const void* g) {
    __builtin_amdgcn_global_load_lds(
        (const __attribute__((address_space(1))) unsigned int*)g,
        (__attribute__((address_space(3))) unsigned int*)lds, 16, 0, 2);
}

// ---------------- kernel 1: patch gather -> bf16 A natural [m][K] layout ---------
__global__ void extract_kernel(const float* __restrict__ x,
                               const int* __restrict__ cent,
                               unsigned short* __restrict__ Af) {
    int m = blockIdx.x;            // 0..127  (b*64+n)
    int c = blockIdx.y;            // 0..31
    int b = m >> 6, n = m & 63;
    int cx = cent[(b * NN + n) * 3 + 0];
    int cy = cent[(b * NN + n) * 3 + 1];
    int cz = cent[(b * NN + n) * 3 + 2];
    int sx = max(cx - 7, 0), ex = min(cx + 8, 96);
    int sy = max(cy - 7, 0), ey = min(cy + 8, 96);
    int sz = max(cz - 7, 0), ez = min(cz + 8, 96);
    const float* xb = x + (size_t)(b * C_ + c) * (96 * 96 * 96);
    unsigned short* Arow = Af + (size_t)m * K_TOT + (size_t)c * PK;
    for (int k = threadIdx.x; k < PK; k += blockDim.x) {
        int iz = k % 15;
        int t  = k / 15;
        int iy = t % 15;
        int ix = t / 15;
        int hx = sx + ix, wy = sy + iy, dz = sz + iz;
        float v = 0.0f;
        if (hx < ex && wy < ey && dz < ez)
            v = xb[(hx * 96 + wy) * 96 + dz];
        Arow[k] = f2bf(v);
    }
}

// ---------------- kernel 2: split-K GEMM (R13 structure + NT W stream) -----------
// F-tile 256, 8 waves (2/SIMD), triple-buffer lookahead-2, steady vmcnt(10).
// Per wave per step: 4 W half-pair ops (contiguous 1KB rows, NT) + 1 A gather.
// Grid (64,4): id%8 = s%8 -> 4 fx-mates of chunk s share an XCD (full 4KB rows).
__global__ __launch_bounds__(512, 1) void gemm_kernel(const unsigned short* __restrict__ Af,
                                                      const float* __restrict__ W,
                                                      unsigned short* __restrict__ partial,
                                                      int CS) {
    __shared__ __align__(16) unsigned char smem[3 * RBUF];     // 123,648 B
    int s  = blockIdx.x;                       // K-chunk (0..63)
    int fx = blockIdx.y;                       // 0..3 : 256-col F tile
    int st0 = s * CS;
    int st1 = min(st0 + CS, KSTEPS);
    int f0  = fx * 256;

    int tid  = (int)threadIdx.x;
    int wave = tid >> 6, lane = tid & 63;
    int fr = lane & 15, lgrp = lane >> 4;
    int wh = wave >> 2, wf = wave & 3;         // mt-half, f-quarter

    f32x4 acc[4][4];                           // [mt-local][ft]
#pragma unroll
    for (int i = 0; i < 4; ++i)
#pragma unroll
        for (int j = 0; j < 4; ++j) acc[i][j] = (f32x4)(0.0f);

    auto STAGE = [&](int buf, int st) {
        int k0 = st << 5;
        unsigned char* wb = smem + buf * RBUF;
        const float* wsrc = W + (size_t)k0 * F_TOT + f0 + (lane << 2);
#pragma unroll
        for (int r = 0; r < 4; ++r) {
            int row = r * 8 + wave;            // 0..31
            async_copy16_nt(wb + (row >> 1) * WPAIR + (row & 1) * 1024,
                            wsrc + (size_t)row * F_TOT);
        }
        unsigned char* ab = wb + WBUF;
        const unsigned short* ag = Af + (size_t)(wave * 16 + fr) * K_TOT + k0 + lgrp * 8;
        async_copy16(ab + wave * 1024, ag);
    };

    auto COMPUTE = [&](int buf) {
        const unsigned char* wb = smem + buf * RBUF;
        const unsigned char* ab = wb + WBUF;
        bf16x8 afrag[4];
#pragma unroll
        for (int i = 0; i < 4; ++i)         // ds_read_b128, lane-consecutive 16B
            afrag[i] = *reinterpret_cast<const bf16x8*>(ab + (wh * 4 + i) * 1024 + lane * 16);
#pragma unroll
        for (int ft = 0; ft < 4; ++ft) {
            int fl4 = (wf * 64 + ft * 16 + fr) * 4;
            float wv[8];
#pragma unroll
            for (int j = 0; j < 8; ++j) {
                int row = lgrp * 8 + j;
                wv[j] = *reinterpret_cast<const float*>(
                            wb + (row >> 1) * WPAIR + (row & 1) * 1024 + fl4);
            }
            ushort8 bt;
#pragma unroll
            for (int j = 0; j < 8; ++j) bt[j] = f2bf(wv[j]);
            bf16x8 bfrag = __builtin_bit_cast(bf16x8, bt);
#pragma unroll
            for (int i = 0; i < 4; ++i)
                acc[i][ft] = __builtin_amdgcn_mfma_f32_16x16x32_bf16(afrag[i], bfrag, acc[i][ft], 0, 0, 0);
        }
    };

    int len = st1 - st0;
    STAGE(0, st0);
    if (len > 1) STAGE(1, st0 + 1);
    int t = st0, cb = 0;
    for (; t + 2 < st1; ++t) {
        int sb = cb + 2; if (sb >= 3) sb -= 3;
        STAGE(sb, t + 2);
        asm volatile("s_waitcnt vmcnt(10)" ::: "memory");  // stage(t) done; t+1,t+2 in flight
        __builtin_amdgcn_s_barrier();
        COMPUTE(cb);
        __builtin_amdgcn_s_barrier();
        if (++cb == 3) cb = 0;
    }
    if (t + 1 < st1) {
        asm volatile("s_waitcnt vmcnt(5)" ::: "memory");
        __builtin_amdgcn_s_barrier();
        COMPUTE(cb);
        __builtin_amdgcn_s_barrier();
        if (++cb == 3) cb = 0;
        ++t;
    }
    asm volatile("s_waitcnt vmcnt(0)" ::: "memory");
    __builtin_amdgcn_s_barrier();
    COMPUTE(cb);

    // --- write bf16 partials: D row = lgrp*4 + r, col = fr (m89 mapping) ---
    unsigned short* pout = partial + (size_t)s * (M_TOT * F_TOT);
#pragma unroll
    for (int i = 0; i < 4; ++i) {
        int mbase = (wh * 4 + i) * 16 + lgrp * 4;
#pragma unroll
        for (int ft = 0; ft < 4; ++ft) {
            int f = f0 + wf * 64 + ft * 16 + fr;
#pragma unroll
            for (int r = 0; r < 4; ++r)
                pout[(size_t)(mbase + r) * F_TOT + f] = f2bf(acc[i][ft][r]);
        }
    }
}

// ---------------- kernel 3: split-K reduce (bf16 partials) + bias ----------------
__global__ void reduce_kernel(const unsigned short* __restrict__ partial,
                              const float* __restrict__ bias,
                              float* __restrict__ out, int S) {
    int i8 = (blockIdx.x * blockDim.x + threadIdx.x) * 8;
    if (i8 >= M_TOT * F_TOT) return;
    f32x4 b0 = *reinterpret_cast<const f32x4*>(bias + (i8 & (F_TOT - 1)));
    f32x4 b1 = *reinterpret_cast<const f32x4*>(bias + (i8 & (F_TOT - 1)) + 4);
    float a[8] = {b0.x, b0.y, b0.z, b0.w, b1.x, b1.y, b1.z, b1.w};
    for (int s = 0; s < S; ++s) {
        ushort8 p = *reinterpret_cast<const ushort8*>(partial + (size_t)s * (M_TOT * F_TOT) + i8);
#pragma unroll
        for (int j = 0; j < 8; ++j)
            a[j] += __builtin_bit_cast(float, (unsigned int)p[j] << 16);
    }
#pragma unroll
    for (int j = 0; j < 8; ++j) out[i8 + j] = a[j];
}

extern "C" void kernel_launch(void* const* d_in, const int* in_sizes, int n_in,
                              void* d_out, int out_size, void* d_ws, size_t ws_size,
                              hipStream_t stream) {
    const float* x    = (const float*)d_in[0];
    const int*   cent = (const int*)d_in[1];
    const float* W    = (const float*)d_in[2];
    const float* bias = (const float*)d_in[3];
    float* out = (float*)d_out;

    unsigned short* Af = (unsigned short*)d_ws;
    size_t Af_bytes = (size_t)M_TOT * K_TOT * 2;                 // 27,648,000
    unsigned short* partial = (unsigned short*)((char*)d_ws + Af_bytes);

    size_t avail = ws_size > Af_bytes ? ws_size - Af_bytes : 0;
    int S = (int)(avail / ((size_t)M_TOT * F_TOT * 2));
    if (S > 64) S = 64;                   // grid (64,4) = 256 blocks = 1/CU
    if (S < 1)  S = 1;
    int CS = (KSTEPS + S - 1) / S;        // 53 for S=64
    S = (KSTEPS + CS - 1) / CS;           // 64 (last chunk = 36 steps)

    extract_kernel<<<dim3(M_TOT, C_), 256, 0, stream>>>(x, cent, Af);
    gemm_kernel<<<dim3(S, 4), 512, 0, stream>>>(Af, W, partial, CS);
    reduce_kernel<<<dim3((M_TOT * F_TOT) / (256 * 8)), 256, 0, stream>>>(partial, bias, out, S);
}